// Round 2
// baseline (583.835 us; speedup 1.0000x reference)
//
#include <hip/hip_runtime.h>
#include <stdint.h>
#include <math.h>

#define NROW 32768
#define MCOL 2048
#define KDIM 128
#define NHEAD 8
#define SCALE 0.08838834764831845f  /* 1/sqrt(128) */

// ---------------- JAX threefry2x32, key = (0, 42) ----------------
__device__ __forceinline__ void tf2x32(uint32_t x0, uint32_t x1,
                                       uint32_t& o0, uint32_t& o1) {
  const uint32_t K0 = 0u, K1 = 42u, K2 = 0x1BD11BDAu ^ 0u ^ 42u;
  x0 += K0; x1 += K1;
#define TFROUND(r) { x0 += x1; x1 = (x1 << (r)) | (x1 >> (32 - (r))); x1 ^= x0; }
  TFROUND(13) TFROUND(15) TFROUND(26) TFROUND(6)
  x0 += K1; x1 += K2 + 1u;
  TFROUND(17) TFROUND(29) TFROUND(16) TFROUND(24)
  x0 += K2; x1 += K0 + 2u;
  TFROUND(13) TFROUND(15) TFROUND(26) TFROUND(6)
  x0 += K0; x1 += K1 + 3u;
  TFROUND(17) TFROUND(29) TFROUND(16) TFROUND(24)
  x0 += K1; x1 += K2 + 4u;
  TFROUND(13) TFROUND(15) TFROUND(26) TFROUND(6)
  x0 += K2; x1 += K0 + 5u;
#undef TFROUND
  o0 = x0; o1 = x1;
}

// JAX uniform(minval=tiny, maxval=1) bit path
__device__ __forceinline__ float bits_to_u(uint32_t b) {
  uint32_t fb = (b >> 9) | 0x3F800000u;
  float f = __uint_as_float(fb) - 1.0f;
  return (f == 0.0f) ? 1.17549435e-38f : f;
}

// ---------------- precompute: Wsum[d][e] = sum_h Wq[h*128+d][e]; bsum = 2*sum_h bq ----------------
__global__ void k_wsum(const float* __restrict__ Wq, const float* __restrict__ bq,
                       float* __restrict__ Wsum, float* __restrict__ bsum) {
  int t = blockIdx.x * 256 + threadIdx.x;
  if (t < KDIM * KDIM) {
    int d = t >> 7, e = t & 127;
    float s = 0.f;
#pragma unroll
    for (int h = 0; h < NHEAD; ++h) s += Wq[(h * KDIM + d) * KDIM + e];
    Wsum[t] = s;
  }
  if (blockIdx.x == 0 && threadIdx.x < KDIM) {
    int d = threadIdx.x;
    float s = 0.f;
#pragma unroll
    for (int h = 0; h < NHEAD; ++h) s += bq[h * KDIM + d];
    bsum[d] = 2.0f * s;
  }
}

// ---------------- precompute: cw[m][e] = sum_d c[m][d]*Wsum[d][e]; cb[m] = sum_d bsum[d]*c[m][d] ----------------
__global__ void k_cw(const float* __restrict__ c, const float* __restrict__ Wsum,
                     const float* __restrict__ bsum,
                     float* __restrict__ cwT, float* __restrict__ cw_rm,
                     float* __restrict__ cb) {
  int m = blockIdx.x;
  int e = threadIdx.x;  // 128 threads
  __shared__ float crow[KDIM];
  if (e < 32) ((float4*)crow)[e] = ((const float4*)(c + (size_t)m * KDIM))[e];
  __syncthreads();
  float s = 0.f;
#pragma unroll 4
  for (int d = 0; d < KDIM; ++d) s += crow[d] * Wsum[d * KDIM + e];
  cw_rm[(size_t)m * KDIM + e] = s;
  cwT[(size_t)e * MCOL + m] = s;
  if (e == 0) {
    float sb = 0.f;
    for (int d = 0; d < KDIM; ++d) sb += bsum[d] * crow[d];
    cb[m] = sb;
  }
}

// ---------------- main: logits GEMM + online softmax stats + threefry gumbel argmax ----------------
// 512 blocks x 256 threads. Block b handles rows [R, R+64), R = 64*b.
__launch_bounds__(256, 2)
__global__ void k_main(const float* __restrict__ x1, const float* __restrict__ kin,
                       const float* __restrict__ cwT, const float* __restrict__ cw_rm,
                       const float* __restrict__ cb, int* __restrict__ idxOut) {
  __shared__ float xk_lds[KDIM][64];   // [k][local row]  32KB
  __shared__ float cw_lds[32][256];    // [k-sub][m]      32KB  (row 0 reused as rowstats later)

  const int tid = threadIdx.x;
  const int R = blockIdx.x * 64;

  // ---- stage xk = x1 + k, layout [k][row] ----
  {
    int i = tid >> 2;       // local row 0..63
    int sub = tid & 3;
    int grow = R + i;
    const float4* xr = (const float4*)(x1 + (size_t)grow * KDIM);
    const float4* kr = (const float4*)(kin + (size_t)grow * KDIM);
#pragma unroll
    for (int rep = 0; rep < 8; ++rep) {
      int kq = sub + 4 * rep;  // 0..31
      float4 a = xr[kq], b = kr[kq];
      xk_lds[kq * 4 + 0][i] = a.x + b.x;
      xk_lds[kq * 4 + 1][i] = a.y + b.y;
      xk_lds[kq * 4 + 2][i] = a.z + b.z;
      xk_lds[kq * 4 + 3][i] = a.w + b.w;
    }
  }

  const int tr = tid >> 5;   // 0..7
  const int tc = tid & 31;   // 0..31

  float mxs[8], Ds[8];
#pragma unroll
  for (int q = 0; q < 8; ++q) { mxs[q] = -INFINITY; Ds[q] = 0.f; }

  for (int mb = 0; mb < 8; ++mb) {
    const int mB = mb * 256;
    float acc[8][8];
#pragma unroll
    for (int q = 0; q < 8; ++q)
#pragma unroll
      for (int j = 0; j < 8; ++j) acc[q][j] = 0.f;

    float cbv[8];
#pragma unroll
    for (int j = 0; j < 8; ++j) cbv[j] = cb[mB + tc + 32 * j];

    for (int kc = 0; kc < 4; ++kc) {
      __syncthreads();
      {
        int mm4 = tid & 63, kk0 = tid >> 6;
#pragma unroll
        for (int rep = 0; rep < 8; ++rep) {
          int kk = kk0 + 4 * rep;
          float4 v = *(const float4*)(cwT + (size_t)(kc * 32 + kk) * MCOL + mB + mm4 * 4);
          *(float4*)&cw_lds[kk][mm4 * 4] = v;
        }
      }
      __syncthreads();
#pragma unroll 4
      for (int kk = 0; kk < 32; ++kk) {
        const int kg = kc * 32 + kk;
        float4 aL = *(const float4*)&xk_lds[kg][tr * 4];
        float4 aH = *(const float4*)&xk_lds[kg][32 + tr * 4];
        float b[8];
#pragma unroll
        for (int j = 0; j < 8; ++j) b[j] = cw_lds[kk][tc + 32 * j];
#pragma unroll
        for (int j = 0; j < 8; ++j) {
          acc[0][j] += aL.x * b[j];
          acc[1][j] += aL.y * b[j];
          acc[2][j] += aL.z * b[j];
          acc[3][j] += aL.w * b[j];
          acc[4][j] += aH.x * b[j];
          acc[5][j] += aH.y * b[j];
          acc[6][j] += aH.z * b[j];
          acc[7][j] += aH.w * b[j];
        }
      }
    }

    // online softmax stats over this m-block
#pragma unroll
    for (int q = 0; q < 8; ++q) {
      float l[8];
#pragma unroll
      for (int j = 0; j < 8; ++j) l[j] = (acc[q][j] + cbv[j]) * SCALE;
      float bm = l[0];
#pragma unroll
      for (int j = 1; j < 8; ++j) bm = fmaxf(bm, l[j]);
      float nm = fmaxf(mxs[q], bm);
      float s8 = 0.f;
#pragma unroll
      for (int j = 0; j < 8; ++j) s8 += __expf(l[j] - nm);
      Ds[q] = Ds[q] * __expf(mxs[q] - nm) + s8;
      mxs[q] = nm;
    }
  }

  // merge stats across the 32 tc lanes (same 8 rows per tr group)
#pragma unroll
  for (int q = 0; q < 8; ++q) {
    float mx = mxs[q], D = Ds[q];
#pragma unroll
    for (int s = 1; s < 32; s <<= 1) {
      float omx = __shfl_xor(mx, s);
      float oD = __shfl_xor(D, s);
      float nm = fmaxf(mx, omx);
      D = D * __expf(mx - nm) + oD * __expf(omx - nm);
      mx = nm;
    }
    mxs[q] = mx; Ds[q] = D;
  }

  __syncthreads();  // all done reading cw_lds; reuse row 0 for rowstats
  float* rs_mx = &cw_lds[0][0];
  float* rs_D  = &cw_lds[0][64];
  if (tc == 0) {
#pragma unroll
    for (int q = 0; q < 8; ++q) {
      int lr = (q < 4) ? (tr * 4 + q) : (32 + tr * 4 + (q - 4));
      rs_mx[lr] = mxs[q]; rs_D[lr] = Ds[q];
    }
  }
  __syncthreads();

  // ---- PRNG phase (JAX partitionable threefry): element (n,m) -> p = n*2048+m,
  //      block = tf(hi32(p)=0, lo32(p)), bits = o0 ^ o1. Each wave: 16 rows. ----
  const int w = tid >> 6, lane = tid & 63;

  for (int pp = 0; pp < 16; ++pp) {
    const int pr = w * 16 + pp;  // local row 0..63
    const uint32_t base = (uint32_t)(R + pr) * (uint32_t)MCOL;
    float u0 = -1.f, u1 = -1.f, u2 = -1.f;
    int m0 = 0, m1 = 0, m2 = 0;
    for (int jj = 0; jj < 32; ++jj) {
      uint32_t m = (uint32_t)lane + 64u * (uint32_t)jj;
      uint32_t o0, o1;
      tf2x32(0u, base + m, o0, o1);
      float u = bits_to_u(o0 ^ o1);
      if (u > u0)      { u2=u1; m2=m1; u1=u0; m1=m0; u0=u; m0=(int)m; }
      else if (u > u1) { u2=u1; m2=m1; u1=u; m1=(int)m; }
      else if (u > u2) { u2=u; m2=(int)m; }
    }

    {
      const int lrow = pr;
      float mx = rs_mx[lrow], D = rs_D[lrow];
      float g0 = (u0 > 0.f) ? -logf(-logf(u0)) : -INFINITY;
      float g1 = (u1 > 0.f) ? -logf(-logf(u1)) : -INFINITY;
      float g2 = (u2 > 0.f) ? -logf(-logf(u2)) : -INFINITY;
      float gmax = g0;
#pragma unroll
      for (int s = 1; s < 64; s <<= 1) gmax = fmaxf(gmax, __shfl_xor(gmax, s));
      float thresh = gmax - (1.0f / D) - 1e-4f;
      float bs = -INFINITY; int bmi = 0x7FFFFFFF;
      auto cand = [&](float g, int m) {
        if (g >= thresh) {
          const float4* cwm = (const float4*)(cw_rm + (size_t)m * KDIM);
          float l = 0.f;
#pragma unroll
          for (int e4 = 0; e4 < 32; ++e4) {
            float4 cv = cwm[e4];
            l += cv.x * xk_lds[4 * e4 + 0][lrow];
            l += cv.y * xk_lds[4 * e4 + 1][lrow];
            l += cv.z * xk_lds[4 * e4 + 2][lrow];
            l += cv.w * xk_lds[4 * e4 + 3][lrow];
          }
          float lsc = (l + cb[m]) * SCALE;
          float p = expf(lsc - mx) / D;
          float sc = p + g;
          if (sc > bs || (sc == bs && m < bmi)) { bs = sc; bmi = m; }
        }
      };
      cand(g0, m0); cand(g1, m1); cand(g2, m2);
#pragma unroll
      for (int s = 1; s < 64; s <<= 1) {
        float os = __shfl_xor(bs, s);
        int om = __shfl_xor(bmi, s);
        if (os > bs || (os == bs && om < bmi)) { bs = os; bmi = om; }
      }
      if (lane == 0) idxOut[R + pr] = bmi;
    }
  }
}

// ---------------- scatter: acc[idx[n]] += x1[n] ----------------
__global__ void k_scatter(const float* __restrict__ x1, const int* __restrict__ idxArr,
                          float* __restrict__ acc) {
  int t = blockIdx.x * 256 + threadIdx.x;
  int n = t >> 5;
  int e0 = (t & 31) * 4;
  if (n >= NROW) return;
  int m = idxArr[n];
  if (m < 0 || m >= MCOL) return;  // safety: never scatter OOB
  float4 v = *(const float4*)(x1 + (size_t)n * KDIM + e0);
  float* dst = acc + (size_t)m * KDIM + e0;
  atomicAdd(dst + 0, v.x);
  atomicAdd(dst + 1, v.y);
  atomicAdd(dst + 2, v.z);
  atomicAdd(dst + 3, v.w);
}

// ---------------- final: out = acc @ Wd.T + bd ----------------
__global__ void k_final(const float* __restrict__ acc, const float* __restrict__ Wd,
                        const float* __restrict__ bd, float* __restrict__ out) {
  int m = blockIdx.x, j = threadIdx.x;  // 128 threads
  __shared__ float ar[KDIM];
  if (j < 32) ((float4*)ar)[j] = ((const float4*)(acc + (size_t)m * KDIM))[j];
  __syncthreads();
  const float4* wr = (const float4*)(Wd + (size_t)j * KDIM);
  float s = 0.f;
#pragma unroll
  for (int e4 = 0; e4 < 32; ++e4) {
    float4 wv = wr[e4];
    s += wv.x * ar[4 * e4 + 0] + wv.y * ar[4 * e4 + 1]
       + wv.z * ar[4 * e4 + 2] + wv.w * ar[4 * e4 + 3];
  }
  out[(size_t)m * KDIM + j] = s + bd[j];
}

extern "C" void kernel_launch(void* const* d_in, const int* in_sizes, int n_in,
                              void* d_out, int out_size, void* d_ws, size_t ws_size,
                              hipStream_t stream) {
  const float* x1 = (const float*)d_in[0];
  const float* k  = (const float*)d_in[1];
  const float* c  = (const float*)d_in[2];
  const float* Wq = (const float*)d_in[3];
  const float* bq = (const float*)d_in[4];
  const float* Wd = (const float*)d_in[5];
  const float* bd = (const float*)d_in[6];
  float* out = (float*)d_out;

  char* ws = (char*)d_ws;
  float* cwT   = (float*)(ws);                                    // 128*2048 f32 = 1MB
  float* cw_rm = (float*)(ws + (1 << 20));                        // 2048*128 f32 = 1MB
  float* cb    = (float*)(ws + (2 << 20));                        // 2048 f32 = 8KB
  float* Wsum  = (float*)(ws + (2 << 20) + 8192);                 // 16384 f32 = 64KB
  float* bsum  = (float*)(ws + (2 << 20) + 8192 + 65536);         // 128 f32 = 512B
  int*   idxA  = (int*)  (ws + (2 << 20) + 8192 + 65536 + 512);   // 32768 i32 = 128KB
  float* accum = (float*)(ws + (2 << 20) + 8192 + 65536 + 512 + 131072);  // 2048*128 f32 = 1MB

  hipMemsetAsync(accum, 0, (size_t)MCOL * KDIM * sizeof(float), stream);
  k_wsum<<<64, 256, 0, stream>>>(Wq, bq, Wsum, bsum);
  k_cw<<<MCOL, 128, 0, stream>>>(c, Wsum, bsum, cwT, cw_rm, cb);
  k_main<<<512, 256, 0, stream>>>(x1, k, cwT, cw_rm, cb, idxA);
  k_scatter<<<NROW * 32 / 256, 256, 0, stream>>>(x1, idxA, accum);
  k_final<<<MCOL, 128, 0, stream>>>(accum, Wd, bd, out);
}

// Round 3
// 254.292 us; speedup vs baseline: 2.2959x; 2.2959x over previous
//
#include <hip/hip_runtime.h>
#include <stdint.h>
#include <math.h>

#define NROW 32768
#define MCOL 2048
#define KDIM 128
#define NHEAD 8
#define SCALE 0.08838834764831845f  /* 1/sqrt(128) */

typedef __attribute__((ext_vector_type(8))) short short8;
typedef __attribute__((ext_vector_type(4))) float f32x4;

// ---------------- JAX threefry2x32, key = (0, 42) ----------------
__device__ __forceinline__ void tf2x32(uint32_t x0, uint32_t x1,
                                       uint32_t& o0, uint32_t& o1) {
  const uint32_t K0 = 0u, K1 = 42u, K2 = 0x1BD11BDAu ^ 0u ^ 42u;
  x0 += K0; x1 += K1;
#define TFROUND(r) { x0 += x1; x1 = (x1 << (r)) | (x1 >> (32 - (r))); x1 ^= x0; }
  TFROUND(13) TFROUND(15) TFROUND(26) TFROUND(6)
  x0 += K1; x1 += K2 + 1u;
  TFROUND(17) TFROUND(29) TFROUND(16) TFROUND(24)
  x0 += K2; x1 += K0 + 2u;
  TFROUND(13) TFROUND(15) TFROUND(26) TFROUND(6)
  x0 += K0; x1 += K1 + 3u;
  TFROUND(17) TFROUND(29) TFROUND(16) TFROUND(24)
  x0 += K1; x1 += K2 + 4u;
  TFROUND(13) TFROUND(15) TFROUND(26) TFROUND(6)
  x0 += K2; x1 += K0 + 5u;
#undef TFROUND
  o0 = x0; o1 = x1;
}

// JAX uniform(minval=tiny, maxval=1) bit path
__device__ __forceinline__ float bits_to_u(uint32_t b) {
  uint32_t fb = (b >> 9) | 0x3F800000u;
  float f = __uint_as_float(fb) - 1.0f;
  return (f == 0.0f) ? 1.17549435e-38f : f;
}

// ---------------- precompute: Wsum[d][e] = sum_h Wq[h*128+d][e]; bsum = 2*sum_h bq ----------------
__global__ void k_wsum(const float* __restrict__ Wq, const float* __restrict__ bq,
                       float* __restrict__ Wsum, float* __restrict__ bsum) {
  int t = blockIdx.x * 256 + threadIdx.x;
  if (t < KDIM * KDIM) {
    int d = t >> 7, e = t & 127;
    float s = 0.f;
#pragma unroll
    for (int h = 0; h < NHEAD; ++h) s += Wq[(h * KDIM + d) * KDIM + e];
    Wsum[t] = s;
  }
  if (blockIdx.x == 0 && threadIdx.x < KDIM) {
    int d = threadIdx.x;
    float s = 0.f;
#pragma unroll
    for (int h = 0; h < NHEAD; ++h) s += bq[h * KDIM + d];
    bsum[d] = 2.0f * s;
  }
}

// ---------------- precompute: cw_s[m][e] = SCALE * sum_d c[m][d]*Wsum[d][e];
//                  cb_s[m] = SCALE * sum_d bsum[d]*c[m][d];
//                  cwB = bf16 MFMA B-fragment layout of cw_s ----------------
__global__ void k_cw(const float* __restrict__ c, const float* __restrict__ Wsum,
                     const float* __restrict__ bsum,
                     float* __restrict__ cw_s, unsigned short* __restrict__ cwB16,
                     float* __restrict__ cb_s) {
  int m = blockIdx.x;
  int e = threadIdx.x;  // 128 threads
  __shared__ float crow[KDIM];
  if (e < 32) ((float4*)crow)[e] = ((const float4*)(c + (size_t)m * KDIM))[e];
  __syncthreads();
  float s = 0.f;
#pragma unroll 4
  for (int d = 0; d < KDIM; ++d) s += crow[d] * Wsum[d * KDIM + e];
  float sv = s * SCALE;
  cw_s[(size_t)m * KDIM + e] = sv;
  // B-frag: tile t = m>>4, col = m&15; k = e: ks = e>>5, grp = (e>>3)&3, j = e&7
  // lane = grp*16 + col;  ushort index = (((t*4+ks)*64 + lane)*8 + j)
  {
    int t = m >> 4, col = m & 15, ks = e >> 5, grp = (e >> 3) & 3, j = e & 7;
    int lane = grp * 16 + col;
    cwB16[(((size_t)(t * 4 + ks)) * 64 + lane) * 8 + j] =
        (unsigned short)(__float_as_uint(sv) >> 16);
  }
  if (e == 0) {
    float sb = 0.f;
    for (int d = 0; d < KDIM; ++d) sb += bsum[d] * crow[d];
    cb_s[m] = sb * SCALE;
  }
}

// ---------------- k_stats: bf16 MFMA logits GEMM -> per-row (mx, D'=sum exp(l)) ----------------
// 512 blocks x 256 threads (4 waves). Block: rows [R, R+64); wave w: rows R+16w..+15.
__launch_bounds__(256, 2)
__global__ void k_stats(const float* __restrict__ x1, const float* __restrict__ kin,
                        const uint4* __restrict__ cwB, const float* __restrict__ cb_s,
                        float* __restrict__ rowMx, float* __restrict__ rowD) {
  __shared__ uint4 Blds[4096];  // 64KB: 16 m-tiles * 4 ks * 64 lanes

  const int tid = threadIdx.x;
  const int w = tid >> 6, l = tid & 63;
  const int R = blockIdx.x * 64 + w * 16;
  const int rowA = R + (l & 15);
  const int kbase = (l >> 4) * 8;

  // A-fragments: lane l supplies A[row=l&15][k = ks*32 + (l>>4)*8 + j], j=0..7
  union { uint32_t u[4]; short8 s; } af[4];
#pragma unroll
  for (int ks = 0; ks < 4; ++ks) {
    const float* xp = x1 + (size_t)rowA * KDIM + ks * 32 + kbase;
    const float* kp = kin + (size_t)rowA * KDIM + ks * 32 + kbase;
    float4 a0 = *(const float4*)xp, a1 = *(const float4*)(xp + 4);
    float4 b0 = *(const float4*)kp, b1 = *(const float4*)(kp + 4);
    float f[8] = {a0.x + b0.x, a0.y + b0.y, a0.z + b0.z, a0.w + b0.w,
                  a1.x + b1.x, a1.y + b1.y, a1.z + b1.z, a1.w + b1.w};
#pragma unroll
    for (int r = 0; r < 4; ++r)
      af[ks].u[r] = (__float_as_uint(f[2 * r]) >> 16) |
                    (__float_as_uint(f[2 * r + 1]) & 0xFFFF0000u);
  }

  float mxs[4], Ds[4];
#pragma unroll
  for (int r = 0; r < 4; ++r) { mxs[r] = -INFINITY; Ds[r] = 0.f; }

  for (int ch = 0; ch < 8; ++ch) {
    __syncthreads();
    // stage 16 m-tiles of B-frags (64KB), coalesced
    const uint4* src = cwB + (size_t)ch * 4096;
#pragma unroll
    for (int r = 0; r < 16; ++r) Blds[r * 256 + tid] = src[r * 256 + tid];
    __syncthreads();

#pragma unroll 2
    for (int t = 0; t < 16; ++t) {
      f32x4 acc = {0.f, 0.f, 0.f, 0.f};
#pragma unroll
      for (int ks = 0; ks < 4; ++ks) {
        union { uint4 v; short8 s; } bf;
        bf.v = Blds[(t * 4 + ks) * 64 + l];
        acc = __builtin_amdgcn_mfma_f32_16x16x32_bf16(af[ks].s, bf.s, acc, 0, 0, 0);
      }
      int m = ch * 256 + t * 16 + (l & 15);
      float cbv = cb_s[m];
#pragma unroll
      for (int r = 0; r < 4; ++r) {
        float lv = acc[r] + cbv;   // logit[n = R + (l>>4)*4 + r][m]
        mxs[r] = fmaxf(mxs[r], lv);
        Ds[r] += __expf(lv);
      }
    }
  }

  // reduce over the 16 lanes (l&15) that share the same 4 rows
#pragma unroll
  for (int s = 1; s < 16; s <<= 1) {
#pragma unroll
    for (int r = 0; r < 4; ++r) {
      mxs[r] = fmaxf(mxs[r], __shfl_xor(mxs[r], s));
      Ds[r] += __shfl_xor(Ds[r], s);
    }
  }
  if ((l & 15) == 0) {
#pragma unroll
    for (int r = 0; r < 4; ++r) {
      int n = R + (l >> 4) * 4 + r;
      rowMx[n] = mxs[r];
      rowD[n] = Ds[r];
    }
  }
}

// ---------------- k_prng: threefry scan + top-2 + fixup + fused scatter ----------------
// 1024 blocks x 256 threads; wave per row-group, 8 rows per wave.
__launch_bounds__(256, 4)
__global__ void k_prng(const float* __restrict__ x1, const float* __restrict__ kin,
                       const float* __restrict__ cw_s, const float* __restrict__ cb_s,
                       const float* __restrict__ rowMx, const float* __restrict__ rowD,
                       float* __restrict__ accum) {
  const int lane = threadIdx.x & 63;
  const int wgid = blockIdx.x * 4 + (threadIdx.x >> 6);

  for (int rr = 0; rr < 8; ++rr) {
    const int n = wgid * 8 + rr;
    const uint32_t base = (uint32_t)n * (uint32_t)MCOL;

    uint32_t t0 = 0u, t1 = 0u;
    int m0 = 0, m1 = 0;
#pragma unroll 4
    for (int jj = 0; jj < 32; ++jj) {
      uint32_t mm = (uint32_t)lane + 64u * (uint32_t)jj;
      uint32_t o0, o1;
      tf2x32(0u, base + mm, o0, o1);
      uint32_t b = o0 ^ o1;
      bool gt0 = b > t0;
      bool gt1 = b > t1;
      t1 = gt0 ? t0 : (gt1 ? b : t1);
      m1 = gt0 ? m0 : (gt1 ? (int)mm : m1);
      t0 = gt0 ? b : t0;
      m0 = gt0 ? (int)mm : m0;
    }

    float u0 = bits_to_u(t0), u1 = bits_to_u(t1);
    float g0 = -logf(-logf(u0));
    float g1 = -logf(-logf(u1));
    float gmax = g0;
#pragma unroll
    for (int s = 1; s < 64; s <<= 1) gmax = fmaxf(gmax, __shfl_xor(gmax, s));

    const float mx = rowMx[n], Dp = rowD[n];
    // pmax bound inflated for bf16-stat error (common-mode cancels in p_a vs p_b)
    const float thresh = gmax - (__expf(mx) * 1.05f / Dp + 2e-4f);

    // row data (coalesced: 8B/lane)
    const float2 xa = ((const float2*)(x1 + (size_t)n * KDIM))[lane];
    const float2 xb = ((const float2*)(kin + (size_t)n * KDIM))[lane];
    const float xk0 = xa.x + xb.x, xk1 = xa.y + xb.y;

    float bestSc = -INFINITY;
    int bestM = 0x7FFFFFFF;
#pragma unroll
    for (int ph = 0; ph < 2; ++ph) {
      float g = ph ? g1 : g0;
      int mI = ph ? m1 : m0;
      unsigned long long bl = __ballot(g >= thresh);
      while (bl) {
        int src = __ffsll(bl) - 1;
        bl &= bl - 1ull;
        int m = __shfl(mI, src);
        float gc = __shfl(g, src);
        const float2 cv = ((const float2*)(cw_s + (size_t)m * KDIM))[lane];
        float part = xk0 * cv.x + xk1 * cv.y;
#pragma unroll
        for (int s = 1; s < 64; s <<= 1) part += __shfl_xor(part, s);
        float lv = part + cb_s[m];
        float p = __expf(lv) / Dp;   // = exp(l - mx)/D, since D = D' * exp(-mx)
        float sc = p + gc;
        if (sc > bestSc || (sc == bestSc && m < bestM)) { bestSc = sc; bestM = m; }
      }
    }

    // fused scatter: accum[bestM] += x1[n]
    float* dst = accum + (size_t)bestM * KDIM + lane * 2;
    atomicAdd(dst + 0, xa.x);
    atomicAdd(dst + 1, xa.y);
  }
}

// ---------------- final: out = accum @ Wd.T + bd ----------------
__global__ void k_final(const float* __restrict__ acc, const float* __restrict__ Wd,
                        const float* __restrict__ bd, float* __restrict__ out) {
  int m = blockIdx.x, j = threadIdx.x;  // 128 threads
  __shared__ float ar[KDIM];
  if (j < 32) ((float4*)ar)[j] = ((const float4*)(acc + (size_t)m * KDIM))[j];
  __syncthreads();
  const float4* wr = (const float4*)(Wd + (size_t)j * KDIM);
  float s = 0.f;
#pragma unroll
  for (int e4 = 0; e4 < 32; ++e4) {
    float4 wv = wr[e4];
    s += wv.x * ar[4 * e4 + 0] + wv.y * ar[4 * e4 + 1]
       + wv.z * ar[4 * e4 + 2] + wv.w * ar[4 * e4 + 3];
  }
  out[(size_t)m * KDIM + j] = s + bd[j];
}

extern "C" void kernel_launch(void* const* d_in, const int* in_sizes, int n_in,
                              void* d_out, int out_size, void* d_ws, size_t ws_size,
                              hipStream_t stream) {
  const float* x1 = (const float*)d_in[0];
  const float* k  = (const float*)d_in[1];
  const float* c  = (const float*)d_in[2];
  const float* Wq = (const float*)d_in[3];
  const float* bq = (const float*)d_in[4];
  const float* Wd = (const float*)d_in[5];
  const float* bd = (const float*)d_in[6];
  float* out = (float*)d_out;

  char* ws = (char*)d_ws;
  size_t off = 0;
  float* cw_s = (float*)(ws + off); off += (size_t)MCOL * KDIM * 4;          // 1MB
  float* cb_s = (float*)(ws + off); off += 8192;                             // 8KB
  unsigned short* cwB = (unsigned short*)(ws + off); off += (size_t)MCOL * KDIM * 2; // 512KB
  float* Wsum = (float*)(ws + off); off += KDIM * KDIM * 4;                  // 64KB
  float* bsum = (float*)(ws + off); off += 512;
  float* rowMx = (float*)(ws + off); off += (size_t)NROW * 4;                // 128KB
  float* rowD  = (float*)(ws + off); off += (size_t)NROW * 4;                // 128KB
  float* accum = (float*)(ws + off); off += (size_t)MCOL * KDIM * 4;         // 1MB

  hipMemsetAsync(accum, 0, (size_t)MCOL * KDIM * sizeof(float), stream);
  k_wsum<<<64, 256, 0, stream>>>(Wq, bq, Wsum, bsum);
  k_cw<<<MCOL, 128, 0, stream>>>(c, Wsum, bsum, cw_s, cwB, cb_s);
  k_stats<<<512, 256, 0, stream>>>(x1, k, (const uint4*)cwB, cb_s, rowMx, rowD);
  k_prng<<<1024, 256, 0, stream>>>(x1, k, cw_s, cb_s, rowMx, rowD, accum);
  k_final<<<MCOL, 128, 0, stream>>>(accum, Wd, bd, out);
}